// Round 1
// baseline (1407.608 us; speedup 1.0000x reference)
//
#include <hip/hip_runtime.h>
#include <hip/hip_bf16.h>
#include <math.h>

#define NQ 8192
#define DD 256
#define NHD 8
#define HDD 32
#define PP 25
#define HH 512
#define WW 512
#define HWSZ (HH * WW)
#define DFF 1024

// ---------------------------------------------------------------------------
// Generic GEMM: C[m,n] = act( sum_k A[m,k] * W[n,k] + bias[n] (+ res[m,n]) )
// A: (M,K) row-major. W: (N,K) row-major (i.e. computes A @ W^T).
// BM=BN=128, BK=16, 8x8 per thread, 256 threads. M,K must be mult of 128/16;
// N handled with guards.
// ---------------------------------------------------------------------------
template <int RELU, int ADD_RES, int BF16_OUT>
__global__ __launch_bounds__(256) void gemm_tn(
    const float* __restrict__ A, const float* __restrict__ Wt,
    const float* __restrict__ bias, const float* __restrict__ res,
    void* __restrict__ Cout, int M, int N, int K) {
  __shared__ float As[16][132];  // [k][m], 132 pad keeps 16B align + banks ok
  __shared__ float Bs[16][132];  // [k][n]
  const int tid = threadIdx.x;
  const int bm = blockIdx.x * 128;
  const int bn = blockIdx.y * 128;
  const int tx = tid & 15;   // n-direction
  const int ty = tid >> 4;   // m-direction

  float acc[8][8];
#pragma unroll
  for (int i = 0; i < 8; i++)
#pragma unroll
    for (int j = 0; j < 8; j++) acc[i][j] = 0.f;

  const int lr = tid >> 2;  // 0..63 row
  const int lq = tid & 3;   // quad-of-4-floats within 16-wide k slice

  for (int k0 = 0; k0 < K; k0 += 16) {
#pragma unroll
    for (int h = 0; h < 2; h++) {
      const int row = lr + h * 64;
      const float4 av =
          *(const float4*)(A + (long)(bm + row) * K + k0 + lq * 4);
      As[lq * 4 + 0][row] = av.x;
      As[lq * 4 + 1][row] = av.y;
      As[lq * 4 + 2][row] = av.z;
      As[lq * 4 + 3][row] = av.w;
      const int wrow = bn + row;
      float4 wv = make_float4(0.f, 0.f, 0.f, 0.f);
      if (wrow < N) wv = *(const float4*)(Wt + (long)wrow * K + k0 + lq * 4);
      Bs[lq * 4 + 0][row] = wv.x;
      Bs[lq * 4 + 1][row] = wv.y;
      Bs[lq * 4 + 2][row] = wv.z;
      Bs[lq * 4 + 3][row] = wv.w;
    }
    __syncthreads();
#pragma unroll
    for (int kk = 0; kk < 16; kk++) {
      float a[8], b[8];
#pragma unroll
      for (int i = 0; i < 8; i++) a[i] = As[kk][ty * 8 + i];
#pragma unroll
      for (int j = 0; j < 8; j++) b[j] = Bs[kk][tx * 8 + j];
#pragma unroll
      for (int i = 0; i < 8; i++)
#pragma unroll
        for (int j = 0; j < 8; j++) acc[i][j] += a[i] * b[j];
    }
    __syncthreads();
  }

#pragma unroll
  for (int i = 0; i < 8; i++) {
    const int m = bm + ty * 8 + i;
#pragma unroll
    for (int j = 0; j < 8; j++) {
      const int n = bn + tx * 8 + j;
      if (n < N) {
        float v = acc[i][j] + bias[n];
        if (ADD_RES) v += res[(long)m * N + n];
        if (RELU) v = fmaxf(v, 0.f);
        if (BF16_OUT)
          ((__hip_bfloat16*)Cout)[(long)m * N + n] = __float2bfloat16(v);
        else
          ((float*)Cout)[(long)m * N + n] = v;
      }
    }
  }
}

// ---------------------------------------------------------------------------
// qp1 = relu(ref_windows @ Wp1^T + bp1)   (NQ,8) @ (8,256)
// ---------------------------------------------------------------------------
__global__ __launch_bounds__(256) void qp1_kernel(
    const float* __restrict__ rw, const float* __restrict__ Wp1,
    const float* __restrict__ bp1, float* __restrict__ out) {
  const int m = blockIdx.x;
  const int d = threadIdx.x;
  __shared__ float r[8];
  if (d < 8) r[d] = rw[m * 8 + d];
  __syncthreads();
  float s = bp1[d];
#pragma unroll
  for (int j = 0; j < 8; j++) s += r[j] * Wp1[d * 8 + j];
  out[(long)m * DD + d] = fmaxf(s, 0.f);
}

// ---------------------------------------------------------------------------
// Per-query: softmax(logits over 25 per head) -> attn ; decode boxes+angle
// from off + ref_windows -> 25 sampling locations per head.
// ---------------------------------------------------------------------------
__global__ __launch_bounds__(256) void attn_loc_kernel(
    const float* __restrict__ logits, const float* __restrict__ offp,
    const float* __restrict__ rw, float* __restrict__ attn,
    float* __restrict__ loc) {
  const int m = blockIdx.x;
  const int t = threadIdx.x;
  __shared__ float sl[200];
  __shared__ float soff[40];
  __shared__ float srw[8];
  if (t < 200) sl[t] = logits[(long)m * 200 + t];
  if (t >= 208 && t < 248) soff[t - 208] = offp[(long)m * 40 + (t - 208)];
  if (t >= 200 && t < 208) srw[t - 200] = rw[(long)m * 8 + (t - 200)];
  __syncthreads();
  // softmax per head (8 heads x 25)
  if (t < 8) {
    float mx = -1e30f;
    for (int p = 0; p < 25; p++) mx = fmaxf(mx, sl[t * 25 + p]);
    float s = 0.f;
    for (int p = 0; p < 25; p++) s += __expf(sl[t * 25 + p] - mx);
    const float inv = 1.f / s;
    for (int p = 0; p < 25; p++)
      attn[(long)m * 200 + t * 25 + p] = __expf(sl[t * 25 + p] - mx) * inv;
  }
  // sampling locations
  if (t < 200) {
    const int h = t / 25;
    const int p = t - h * 25;
    const float cx = srw[0], cy = srw[1], w0 = srw[3], h0 = srw[4],
                ra = srw[6];
    const float ob0 = soff[h * 5 + 0], ob1 = soff[h * 5 + 1],
                ob2 = soff[h * 5 + 2], ob3 = soff[h * 5 + 3],
                oa = soff[h * 5 + 4];
    const float ang = (ra + oa * (1.f / 16.f)) * 6.28318530717958647692f;
    const float bx = cx + ob0 * 0.125f * w0;
    const float by = cy + ob1 * 0.125f * h0;
    const float bw = fmaxf(w0 + ob2 * 0.125f * w0, 0.f);
    const float bh = fmaxf(h0 + ob3 * 0.125f * h0, 0.f);
    const float gx = (float)((p % 5) - 2) * 0.2f * bw;  // j component
    const float gy = (float)((p / 5) - 2) * 0.2f * bh;  // i component
    float sn, cs;
    __sincosf(ang, &sn, &cs);
    const float lx = bx + cs * gx - sn * gy;
    const float ly = by + sn * gx + cs * gy;
    loc[((long)m * 200 + t) * 2 + 0] = lx;
    loc[((long)m * 200 + t) * 2 + 1] = ly;
  }
}

// ---------------------------------------------------------------------------
// Bilinear gather + attn-weighted sum over 25 points.
// v: (HW, NH, HD) bf16.  out: (NQ, 256) fp32, channel = h*32+c.
// block = 256: t -> (h = t>>5, c = t&31)
// ---------------------------------------------------------------------------
__global__ __launch_bounds__(256) void sample_kernel(
    const __hip_bfloat16* __restrict__ v, const float* __restrict__ attn,
    const float* __restrict__ loc, float* __restrict__ out) {
  const int m = blockIdx.x;
  const int t = threadIdx.x;
  const int h = t >> 5;
  const int c = t & 31;
  __shared__ float sat[200];
  __shared__ float slc[400];
  if (t < 200) sat[t] = attn[(long)m * 200 + t];
  slc[t] = loc[(long)m * 400 + t];
  if (t < 144) slc[256 + t] = loc[(long)m * 400 + 256 + t];
  __syncthreads();
  float acc = 0.f;
  for (int p = 0; p < 25; p++) {
    const float lx = slc[(h * 25 + p) * 2 + 0];
    const float ly = slc[(h * 25 + p) * 2 + 1];
    const float a = sat[h * 25 + p];
    const float x = lx * (float)WW - 0.5f;
    const float y = ly * (float)HH - 0.5f;
    const float x0 = floorf(x);
    const float y0 = floorf(y);
    float sval = 0.f;
#pragma unroll
    for (int dy = 0; dy < 2; dy++)
#pragma unroll
      for (int dx = 0; dx < 2; dx++) {
        const float xi = x0 + (float)dx;
        const float yi = y0 + (float)dy;
        const float wgt = (1.f - fabsf(x - xi)) * (1.f - fabsf(y - yi));
        const bool valid = (xi >= 0.f) && (xi <= (float)(WW - 1)) &&
                           (yi >= 0.f) && (yi <= (float)(HH - 1));
        const int xc = (int)fminf(fmaxf(xi, 0.f), (float)(WW - 1));
        const int yc = (int)fminf(fmaxf(yi, 0.f), (float)(HH - 1));
        const int idx = yc * WW + xc;
        const float g = __bfloat162float(v[(long)idx * DD + h * HDD + c]);
        sval += (valid ? wgt : 0.f) * g;
      }
    acc += a * sval;
  }
  out[(long)m * DD + t] = acc;
}

// ---------------------------------------------------------------------------
// LayerNorm over D=256: out = LN(x + resid) * g + b
// ---------------------------------------------------------------------------
__global__ __launch_bounds__(256) void ln_kernel(
    const float* __restrict__ x, const float* __restrict__ resid,
    const float* __restrict__ g, const float* __restrict__ b,
    float* __restrict__ out) {
  const int m = blockIdx.x;
  const int d = threadIdx.x;
  const float v = x[(long)m * DD + d] + resid[(long)m * DD + d];
  __shared__ float red[256];
  __shared__ float mean_s, inv_s;
  red[d] = v;
  __syncthreads();
  for (int s = 128; s > 0; s >>= 1) {
    if (d < s) red[d] += red[d + s];
    __syncthreads();
  }
  if (d == 0) mean_s = red[0] * (1.f / 256.f);
  __syncthreads();
  const float mu = mean_s;
  const float diff = v - mu;
  red[d] = diff * diff;
  __syncthreads();
  for (int s = 128; s > 0; s >>= 1) {
    if (d < s) red[d] += red[d + s];
    __syncthreads();
  }
  if (d == 0) inv_s = rsqrtf(red[0] * (1.f / 256.f) + 1e-5f);
  __syncthreads();
  out[(long)m * DD + d] = diff * inv_s * g[d] + b[d];
}

// ---------------------------------------------------------------------------
extern "C" void kernel_launch(void* const* d_in, const int* in_sizes, int n_in,
                              void* d_out, int out_size, void* d_ws,
                              size_t ws_size, hipStream_t stream) {
  const float* query = (const float*)d_in[0];
  const float* memory = (const float*)d_in[1];
  const float* rw = (const float*)d_in[2];
  const float* Wp1 = (const float*)d_in[5];
  const float* bp1 = (const float*)d_in[6];
  const float* Wp2 = (const float*)d_in[7];
  const float* bp2 = (const float*)d_in[8];
  const float* Wp3 = (const float*)d_in[9];
  const float* bp3 = (const float*)d_in[10];
  const float* Wv = (const float*)d_in[11];
  const float* bv = (const float*)d_in[12];
  const float* Wa = (const float*)d_in[13];
  const float* ba = (const float*)d_in[14];
  const float* Wb = (const float*)d_in[15];
  const float* bb = (const float*)d_in[16];
  const float* Wo = (const float*)d_in[17];
  const float* bo = (const float*)d_in[18];
  const float* W1 = (const float*)d_in[19];
  const float* b1 = (const float*)d_in[20];
  const float* W2 = (const float*)d_in[21];
  const float* b2 = (const float*)d_in[22];
  const float* g2 = (const float*)d_in[23];
  const float* be2 = (const float*)d_in[24];
  const float* g3 = (const float*)d_in[25];
  const float* be3 = (const float*)d_in[26];

  char* ws = (char*)d_ws;
  size_t off = 0;
  auto alloc = [&](size_t bytes) {
    void* p = ws + off;
    off += (bytes + 255) & ~(size_t)255;
    return p;
  };
  __hip_bfloat16* vbuf = (__hip_bfloat16*)alloc((size_t)HWSZ * DD * 2);  // 134MB
  float* qbuf = (float*)alloc((size_t)NQ * DD * 4);                      // 8MB
  float* locbuf = (float*)alloc((size_t)NQ * 200 * 2 * 4);               // 13MB
  float* attnbuf = (float*)alloc((size_t)NQ * 200 * 4);                  // 6.6MB
  float* offbuf = (float*)alloc((size_t)NQ * 40 * 4);                    // 1.3MB
  float* bufA = (float*)alloc((size_t)NQ * DFF * 4);  // 33.5MB qp1/logits/q2/h1
  float* bufB = (float*)alloc((size_t)NQ * DD * 4);   // 8MB qp2/outattn/f2
  float* xqbuf = (float*)alloc((size_t)NQ * DD * 4);  // 8MB
  (void)ws_size;

  // 1. qp1 = relu(rw @ Wp1^T + bp1)
  qp1_kernel<<<NQ, 256, 0, stream>>>(rw, Wp1, bp1, bufA);
  // 2. qp2 = relu(qp1 @ Wp2^T + bp2)
  gemm_tn<1, 0, 0><<<dim3(NQ / 128, 2), 256, 0, stream>>>(
      bufA, Wp2, bp2, nullptr, bufB, NQ, DD, DD);
  // 3. q = qp2 @ Wp3^T + bp3 + query
  gemm_tn<0, 1, 0><<<dim3(NQ / 128, 2), 256, 0, stream>>>(
      bufB, Wp3, bp3, query, qbuf, NQ, DD, DD);
  // 4. v = memory @ Wv^T + bv  (bf16 out)
  gemm_tn<0, 0, 1><<<dim3(HWSZ / 128, 2), 256, 0, stream>>>(
      memory, Wv, bv, nullptr, vbuf, HWSZ, DD, DD);
  // 5. logits = q @ Wa^T + ba  (N=200)
  gemm_tn<0, 0, 0><<<dim3(NQ / 128, 2), 256, 0, stream>>>(
      qbuf, Wa, ba, nullptr, bufA, NQ, 200, DD);
  // 6. off = q @ Wb^T + bb  (N=40)
  gemm_tn<0, 0, 0><<<dim3(NQ / 128, 1), 256, 0, stream>>>(
      qbuf, Wb, bb, nullptr, offbuf, NQ, 40, DD);
  // 7. softmax + sampling locations
  attn_loc_kernel<<<NQ, 256, 0, stream>>>(bufA, offbuf, rw, attnbuf, locbuf);
  // 8. bilinear sample + attn-weighted sum -> outattn
  sample_kernel<<<NQ, 256, 0, stream>>>(vbuf, attnbuf, locbuf, bufB);
  // 9. q2 = outattn @ Wo^T + bo
  gemm_tn<0, 0, 0><<<dim3(NQ / 128, 2), 256, 0, stream>>>(
      bufB, Wo, bo, nullptr, bufA, NQ, DD, DD);
  // 10. xq = LN(query + q2)
  ln_kernel<<<NQ, 256, 0, stream>>>(bufA, query, g2, be2, xqbuf);
  // 11. h1 = relu(xq @ W1^T + b1)  (N=1024)
  gemm_tn<1, 0, 0><<<dim3(NQ / 128, 8), 256, 0, stream>>>(
      xqbuf, W1, b1, nullptr, bufA, NQ, DFF, DD);
  // 12. f2 = h1 @ W2^T + b2  (K=1024)
  gemm_tn<0, 0, 0><<<dim3(NQ / 128, 2), 256, 0, stream>>>(
      bufA, W2, b2, nullptr, bufB, NQ, DD, DFF);
  // 13. out = LN(xq + f2)
  ln_kernel<<<NQ, 256, 0, stream>>>(bufB, xqbuf, g3, be3, (float*)d_out);
}

// Round 2
// 778.078 us; speedup vs baseline: 1.8091x; 1.8091x over previous
//
#include <hip/hip_runtime.h>
#include <hip/hip_bf16.h>
#include <math.h>

#define NQ 8192
#define DD 256
#define NHD 8
#define HDD 32
#define PP 25
#define HH 512
#define WW 512
#define HWSZ (HH * WW)
#define DFF 1024

typedef __bf16 bf16_t;
typedef bf16_t bf16x8 __attribute__((ext_vector_type(8)));
typedef bf16_t bf16x4 __attribute__((ext_vector_type(4)));
typedef float f32x4 __attribute__((ext_vector_type(4)));

// ---------------------------------------------------------------------------
// MFMA GEMM: C[m,n] = act( A(M,K) @ W(N,K)^T + bias (+res) )
// BM=BN=128, BK=32, 256 threads = 4 waves (2x2), each wave 64x64 via 4x4
// mfma_f32_16x16x32_bf16 tiles. A path: bf16 via global_load_lds(16B) or
// fp32 via VGPR->cvt->ds_write (fused cast, used for the memory@Wv GEMM).
// W is always bf16 via global_load_lds. N edge handled by clamping W rows
// (reads valid memory; results masked at store). M, K must be mult of 128/32.
// ---------------------------------------------------------------------------
template <int A_F32, int RELU, int ADD_RES, int BF16_OUT>
__global__ __launch_bounds__(256) void gemm_mfma(
    const void* __restrict__ Av, const bf16_t* __restrict__ Wt,
    const float* __restrict__ bias, const float* __restrict__ res,
    void* __restrict__ Cout, int M, int N, int K) {
  __shared__ bf16_t As[128][32];
  __shared__ bf16_t Bs[128][32];
  const int tid = threadIdx.x;
  const int bn = blockIdx.x * 128;
  const int bm = blockIdx.y * 128;
  const int wave = tid >> 6;
  const int lane = tid & 63;
  const int l15 = lane & 15;
  const int quad = lane >> 4;
  const int wm = (wave & 1) * 64;
  const int wn = (wave >> 1) * 64;

  f32x4 acc[4][4];
#pragma unroll
  for (int i = 0; i < 4; i++)
#pragma unroll
    for (int j = 0; j < 4; j++) acc[i][j] = (f32x4){0.f, 0.f, 0.f, 0.f};

  // staging indices (bf16 glds path): thread t -> row (per 64-half), k-offset
  const int srow = tid >> 2;       // 0..63
  const int skq = (tid & 3) * 8;   // element offset in 32-wide K slice

  for (int k0 = 0; k0 < K; k0 += 32) {
    if (A_F32) {
      const float* A = (const float*)Av;
#pragma unroll
      for (int c = 0; c < 4; c++) {
        const int id = c * 256 + tid;
        const int row = id >> 3;
        const int kq = (id & 7) * 4;
        const float4 av = *(const float4*)(A + (long)(bm + row) * K + k0 + kq);
        bf16x4 bv;
        bv[0] = (bf16_t)av.x;
        bv[1] = (bf16_t)av.y;
        bv[2] = (bf16_t)av.z;
        bv[3] = (bf16_t)av.w;
        *(bf16x4*)&As[row][kq] = bv;
      }
    } else {
      const bf16_t* A = (const bf16_t*)Av;
#pragma unroll
      for (int c = 0; c < 2; c++) {
        const int row = c * 64 + srow;
        const bf16_t* gp = A + (long)(bm + row) * K + k0 + skq;
        bf16_t* lp = &As[0][0] + (c * 2048 + wave * 512);  // wave-uniform base
        __builtin_amdgcn_global_load_lds(
            (const __attribute__((address_space(1))) void*)gp,
            (__attribute__((address_space(3))) void*)lp, 16, 0, 0);
      }
    }
#pragma unroll
    for (int c = 0; c < 2; c++) {
      const int row = c * 64 + srow;
      int wrow = bn + row;
      if (wrow >= N) wrow = N - 1;  // clamp: valid mem, masked at store
      const bf16_t* gp = Wt + (long)wrow * K + k0 + skq;
      bf16_t* lp = &Bs[0][0] + (c * 2048 + wave * 512);
      __builtin_amdgcn_global_load_lds(
          (const __attribute__((address_space(1))) void*)gp,
          (__attribute__((address_space(3))) void*)lp, 16, 0, 0);
    }
    __syncthreads();
    bf16x8 af[4], bfr[4];
#pragma unroll
    for (int i = 0; i < 4; i++)
      af[i] = *(bf16x8*)&As[wm + i * 16 + l15][quad * 8];
#pragma unroll
    for (int j = 0; j < 4; j++)
      bfr[j] = *(bf16x8*)&Bs[wn + j * 16 + l15][quad * 8];
#pragma unroll
    for (int i = 0; i < 4; i++)
#pragma unroll
      for (int j = 0; j < 4; j++)
        acc[i][j] = __builtin_amdgcn_mfma_f32_16x16x32_bf16(af[i], bfr[j],
                                                            acc[i][j], 0, 0, 0);
    __syncthreads();
  }

  // epilogue: D[row=quad*4+r][col=l15] per 16x16 tile (m89/m91 layout)
  float bsv[4];
#pragma unroll
  for (int j = 0; j < 4; j++) {
    const int n = bn + wn + j * 16 + l15;
    bsv[j] = (n < N) ? bias[n] : 0.f;
  }
#pragma unroll
  for (int i = 0; i < 4; i++) {
#pragma unroll
    for (int r = 0; r < 4; r++) {
      const int m = bm + wm + i * 16 + quad * 4 + r;
#pragma unroll
      for (int j = 0; j < 4; j++) {
        const int n = bn + wn + j * 16 + l15;
        if (n < N) {
          float v = acc[i][j][r] + bsv[j];
          if (ADD_RES) v += res[(long)m * N + n];
          if (RELU) v = fmaxf(v, 0.f);
          if (BF16_OUT)
            ((__hip_bfloat16*)Cout)[(long)m * N + n] = __float2bfloat16(v);
          else
            ((float*)Cout)[(long)m * N + n] = v;
        }
      }
    }
  }
}

// ---------------------------------------------------------------------------
// Weight fp32 -> bf16 casts, 8 segments in one kernel. All lens mult of 1024.
// ---------------------------------------------------------------------------
struct CastArgs {
  const float* src[8];
  __hip_bfloat16* dst[8];
  int len[8];
};
__global__ __launch_bounds__(256) void cast_weights(CastArgs a) {
  const int seg = blockIdx.y;
  const int base = blockIdx.x * 1024 + threadIdx.x * 4;
  if (base >= a.len[seg]) return;
  const float4 v = *(const float4*)(a.src[seg] + base);
  __hip_bfloat16* d = a.dst[seg] + base;
  d[0] = __float2bfloat16(v.x);
  d[1] = __float2bfloat16(v.y);
  d[2] = __float2bfloat16(v.z);
  d[3] = __float2bfloat16(v.w);
}

// ---------------------------------------------------------------------------
// qp1 = relu(ref_windows @ Wp1^T + bp1)   (NQ,8) @ (8,256) -> bf16
// ---------------------------------------------------------------------------
__global__ __launch_bounds__(256) void qp1_kernel(
    const float* __restrict__ rw, const float* __restrict__ Wp1,
    const float* __restrict__ bp1, __hip_bfloat16* __restrict__ out) {
  const int m = blockIdx.x;
  const int d = threadIdx.x;
  __shared__ float r[8];
  if (d < 8) r[d] = rw[m * 8 + d];
  __syncthreads();
  float s = bp1[d];
#pragma unroll
  for (int j = 0; j < 8; j++) s += r[j] * Wp1[d * 8 + j];
  out[(long)m * DD + d] = __float2bfloat16(fmaxf(s, 0.f));
}

// ---------------------------------------------------------------------------
// Per-query: softmax over 25 per head -> attn; decode sampling locations.
// ---------------------------------------------------------------------------
__global__ __launch_bounds__(256) void attn_loc_kernel(
    const float* __restrict__ logits, const float* __restrict__ offp,
    const float* __restrict__ rw, float* __restrict__ attn,
    float* __restrict__ loc) {
  const int m = blockIdx.x;
  const int t = threadIdx.x;
  __shared__ float sl[200];
  __shared__ float soff[40];
  __shared__ float srw[8];
  if (t < 200) sl[t] = logits[(long)m * 200 + t];
  if (t >= 208 && t < 248) soff[t - 208] = offp[(long)m * 40 + (t - 208)];
  if (t >= 200 && t < 208) srw[t - 200] = rw[(long)m * 8 + (t - 200)];
  __syncthreads();
  if (t < 8) {
    float mx = -1e30f;
    for (int p = 0; p < 25; p++) mx = fmaxf(mx, sl[t * 25 + p]);
    float s = 0.f;
    for (int p = 0; p < 25; p++) s += __expf(sl[t * 25 + p] - mx);
    const float inv = 1.f / s;
    for (int p = 0; p < 25; p++)
      attn[(long)m * 200 + t * 25 + p] = __expf(sl[t * 25 + p] - mx) * inv;
  }
  if (t < 200) {
    const int h = t / 25;
    const int p = t - h * 25;
    const float cx = srw[0], cy = srw[1], w0 = srw[3], h0 = srw[4],
                ra = srw[6];
    const float ob0 = soff[h * 5 + 0], ob1 = soff[h * 5 + 1],
                ob2 = soff[h * 5 + 2], ob3 = soff[h * 5 + 3],
                oa = soff[h * 5 + 4];
    const float ang = (ra + oa * (1.f / 16.f)) * 6.28318530717958647692f;
    const float bx = cx + ob0 * 0.125f * w0;
    const float by = cy + ob1 * 0.125f * h0;
    const float bw = fmaxf(w0 + ob2 * 0.125f * w0, 0.f);
    const float bh = fmaxf(h0 + ob3 * 0.125f * h0, 0.f);
    const float gx = (float)((p % 5) - 2) * 0.2f * bw;
    const float gy = (float)((p / 5) - 2) * 0.2f * bh;
    float sn, cs;
    __sincosf(ang, &sn, &cs);
    loc[((long)m * 200 + t) * 2 + 0] = bx + cs * gx - sn * gy;
    loc[((long)m * 200 + t) * 2 + 1] = by + sn * gx + cs * gy;
  }
}

// ---------------------------------------------------------------------------
// Bilinear gather + attn-weighted sum. v:(HW,256) bf16. out bf16 (NQ,256).
// ---------------------------------------------------------------------------
__global__ __launch_bounds__(256) void sample_kernel(
    const __hip_bfloat16* __restrict__ v, const float* __restrict__ attn,
    const float* __restrict__ loc, __hip_bfloat16* __restrict__ out) {
  const int m = blockIdx.x;
  const int t = threadIdx.x;
  const int h = t >> 5;
  const int c = t & 31;
  __shared__ float sat[200];
  __shared__ float slc[400];
  if (t < 200) sat[t] = attn[(long)m * 200 + t];
  slc[t] = loc[(long)m * 400 + t];
  if (t < 144) slc[256 + t] = loc[(long)m * 400 + 256 + t];
  __syncthreads();
  float acc = 0.f;
  for (int p = 0; p < 25; p++) {
    const float lx = slc[(h * 25 + p) * 2 + 0];
    const float ly = slc[(h * 25 + p) * 2 + 1];
    const float a = sat[h * 25 + p];
    const float x = lx * (float)WW - 0.5f;
    const float y = ly * (float)HH - 0.5f;
    const float x0 = floorf(x);
    const float y0 = floorf(y);
    float sval = 0.f;
#pragma unroll
    for (int dy = 0; dy < 2; dy++)
#pragma unroll
      for (int dx = 0; dx < 2; dx++) {
        const float xi = x0 + (float)dx;
        const float yi = y0 + (float)dy;
        const float wgt = (1.f - fabsf(x - xi)) * (1.f - fabsf(y - yi));
        const bool valid = (xi >= 0.f) && (xi <= (float)(WW - 1)) &&
                           (yi >= 0.f) && (yi <= (float)(HH - 1));
        const int xc = (int)fminf(fmaxf(xi, 0.f), (float)(WW - 1));
        const int yc = (int)fminf(fmaxf(yi, 0.f), (float)(HH - 1));
        const int idx = yc * WW + xc;
        const float g = __bfloat162float(v[(long)idx * DD + h * HDD + c]);
        sval += (valid ? wgt : 0.f) * g;
      }
    acc += a * sval;
  }
  out[(long)m * DD + t] = __float2bfloat16(acc);
}

// ---------------------------------------------------------------------------
// LayerNorm over D=256: fp32 out + optional bf16 out
// ---------------------------------------------------------------------------
__global__ __launch_bounds__(256) void ln_kernel(
    const float* __restrict__ x, const float* __restrict__ resid,
    const float* __restrict__ g, const float* __restrict__ b,
    float* __restrict__ out, __hip_bfloat16* __restrict__ out_bf) {
  const int m = blockIdx.x;
  const int d = threadIdx.x;
  const float v = x[(long)m * DD + d] + resid[(long)m * DD + d];
  __shared__ float red[256];
  __shared__ float mean_s, inv_s;
  red[d] = v;
  __syncthreads();
  for (int s = 128; s > 0; s >>= 1) {
    if (d < s) red[d] += red[d + s];
    __syncthreads();
  }
  if (d == 0) mean_s = red[0] * (1.f / 256.f);
  __syncthreads();
  const float mu = mean_s;
  const float diff = v - mu;
  red[d] = diff * diff;
  __syncthreads();
  for (int s = 128; s > 0; s >>= 1) {
    if (d < s) red[d] += red[d + s];
    __syncthreads();
  }
  if (d == 0) inv_s = rsqrtf(red[0] * (1.f / 256.f) + 1e-5f);
  __syncthreads();
  const float o = diff * inv_s * g[d] + b[d];
  out[(long)m * DD + d] = o;
  if (out_bf) out_bf[(long)m * DD + d] = __float2bfloat16(o);
}

// ---------------------------------------------------------------------------
extern "C" void kernel_launch(void* const* d_in, const int* in_sizes, int n_in,
                              void* d_out, int out_size, void* d_ws,
                              size_t ws_size, hipStream_t stream) {
  const float* query = (const float*)d_in[0];
  const float* memory = (const float*)d_in[1];
  const float* rw = (const float*)d_in[2];
  const float* Wp1 = (const float*)d_in[5];
  const float* bp1 = (const float*)d_in[6];
  const float* Wp2 = (const float*)d_in[7];
  const float* bp2 = (const float*)d_in[8];
  const float* Wp3 = (const float*)d_in[9];
  const float* bp3 = (const float*)d_in[10];
  const float* Wv = (const float*)d_in[11];
  const float* bv = (const float*)d_in[12];
  const float* Wa = (const float*)d_in[13];
  const float* ba = (const float*)d_in[14];
  const float* Wb = (const float*)d_in[15];
  const float* bb = (const float*)d_in[16];
  const float* Wo = (const float*)d_in[17];
  const float* bo = (const float*)d_in[18];
  const float* W1 = (const float*)d_in[19];
  const float* b1 = (const float*)d_in[20];
  const float* W2 = (const float*)d_in[21];
  const float* b2 = (const float*)d_in[22];
  const float* g2 = (const float*)d_in[23];
  const float* be2 = (const float*)d_in[24];
  const float* g3 = (const float*)d_in[25];
  const float* be3 = (const float*)d_in[26];

  char* ws = (char*)d_ws;
  size_t off = 0;
  auto alloc = [&](size_t bytes) {
    void* p = ws + off;
    off += (bytes + 255) & ~(size_t)255;
    return p;
  };
  __hip_bfloat16* vbuf = (__hip_bfloat16*)alloc((size_t)HWSZ * DD * 2); // 134MB
  __hip_bfloat16* qp1bf = (__hip_bfloat16*)alloc((size_t)NQ * DD * 2);
  __hip_bfloat16* qp2bf = (__hip_bfloat16*)alloc((size_t)NQ * DD * 2);
  __hip_bfloat16* qbf = (__hip_bfloat16*)alloc((size_t)NQ * DD * 2);
  __hip_bfloat16* oabf = (__hip_bfloat16*)alloc((size_t)NQ * DD * 2);
  __hip_bfloat16* xqbf = (__hip_bfloat16*)alloc((size_t)NQ * DD * 2);
  __hip_bfloat16* h1bf = (__hip_bfloat16*)alloc((size_t)NQ * DFF * 2); // 16.8MB
  float* xq32 = (float*)alloc((size_t)NQ * DD * 4);
  float* f32buf = (float*)alloc((size_t)NQ * DD * 4);  // logits -> q2 -> f2
  float* offbuf = (float*)alloc((size_t)NQ * 40 * 4);
  float* attnbuf = (float*)alloc((size_t)NQ * 200 * 4);
  float* locbuf = (float*)alloc((size_t)NQ * 200 * 2 * 4);
  __hip_bfloat16* Wp2b = (__hip_bfloat16*)alloc(65536 * 2);
  __hip_bfloat16* Wp3b = (__hip_bfloat16*)alloc(65536 * 2);
  __hip_bfloat16* Wvb = (__hip_bfloat16*)alloc(65536 * 2);
  __hip_bfloat16* Wab = (__hip_bfloat16*)alloc(51200 * 2);
  __hip_bfloat16* Wbb = (__hip_bfloat16*)alloc(10240 * 2);
  __hip_bfloat16* Wob = (__hip_bfloat16*)alloc(65536 * 2);
  __hip_bfloat16* W1b = (__hip_bfloat16*)alloc(262144 * 2);
  __hip_bfloat16* W2b = (__hip_bfloat16*)alloc(262144 * 2);
  (void)ws_size;

  // 0. cast all weights to bf16
  CastArgs ca;
  ca.src[0] = Wp2; ca.dst[0] = Wp2b; ca.len[0] = 65536;
  ca.src[1] = Wp3; ca.dst[1] = Wp3b; ca.len[1] = 65536;
  ca.src[2] = Wv;  ca.dst[2] = Wvb;  ca.len[2] = 65536;
  ca.src[3] = Wa;  ca.dst[3] = Wab;  ca.len[3] = 51200;
  ca.src[4] = Wb;  ca.dst[4] = Wbb;  ca.len[4] = 10240;
  ca.src[5] = Wo;  ca.dst[5] = Wob;  ca.len[5] = 65536;
  ca.src[6] = W1;  ca.dst[6] = W1b;  ca.len[6] = 262144;
  ca.src[7] = W2;  ca.dst[7] = W2b;  ca.len[7] = 262144;
  cast_weights<<<dim3(256, 8), 256, 0, stream>>>(ca);

  // 1. qp1 = relu(rw @ Wp1^T + bp1) -> bf16
  qp1_kernel<<<NQ, 256, 0, stream>>>(rw, Wp1, bp1, qp1bf);
  // 2. qp2 = relu(qp1 @ Wp2^T + bp2) -> bf16
  gemm_mfma<0, 1, 0, 1><<<dim3(2, NQ / 128), 256, 0, stream>>>(
      qp1bf, (const bf16_t*)Wp2b, bp2, nullptr, qp2bf, NQ, DD, DD);
  // 3. q = qp2 @ Wp3^T + bp3 + query -> bf16
  gemm_mfma<0, 0, 1, 1><<<dim3(2, NQ / 128), 256, 0, stream>>>(
      qp2bf, (const bf16_t*)Wp3b, bp3, query, qbf, NQ, DD, DD);
  // 4. v = memory @ Wv^T + bv -> bf16 (fused fp32->bf16 A staging)
  gemm_mfma<1, 0, 0, 1><<<dim3(2, HWSZ / 128), 256, 0, stream>>>(
      memory, (const bf16_t*)Wvb, bv, nullptr, vbuf, HWSZ, DD, DD);
  // 5. logits = q @ Wa^T + ba (N=200, fp32)
  gemm_mfma<0, 0, 0, 0><<<dim3(2, NQ / 128), 256, 0, stream>>>(
      qbf, (const bf16_t*)Wab, ba, nullptr, f32buf, NQ, 200, DD);
  // 6. off = q @ Wb^T + bb (N=40, fp32)
  gemm_mfma<0, 0, 0, 0><<<dim3(1, NQ / 128), 256, 0, stream>>>(
      qbf, (const bf16_t*)Wbb, bb, nullptr, offbuf, NQ, 40, DD);
  // 7. softmax + sampling locations
  attn_loc_kernel<<<NQ, 256, 0, stream>>>(f32buf, offbuf, rw, attnbuf, locbuf);
  // 8. bilinear sample + weighted sum -> bf16
  sample_kernel<<<NQ, 256, 0, stream>>>(vbuf, attnbuf, locbuf, oabf);
  // 9. q2 = outattn @ Wo^T + bo (fp32)
  gemm_mfma<0, 0, 0, 0><<<dim3(2, NQ / 128), 256, 0, stream>>>(
      oabf, (const bf16_t*)Wob, bo, nullptr, f32buf, NQ, DD, DD);
  // 10. xq = LN(query + q2) -> fp32 + bf16
  ln_kernel<<<NQ, 256, 0, stream>>>(f32buf, query, g2, be2, xq32, xqbf);
  // 11. h1 = relu(xq @ W1^T + b1) (N=1024) -> bf16
  gemm_mfma<0, 1, 0, 1><<<dim3(8, NQ / 128), 256, 0, stream>>>(
      xqbf, (const bf16_t*)W1b, b1, nullptr, h1bf, NQ, DFF, DD);
  // 12. f2 = h1 @ W2^T + b2 (K=1024, fp32)
  gemm_mfma<0, 0, 0, 0><<<dim3(2, NQ / 128), 256, 0, stream>>>(
      h1bf, (const bf16_t*)W2b, b2, nullptr, f32buf, NQ, DD, DFF);
  // 13. out = LN(xq + f2)
  ln_kernel<<<NQ, 256, 0, stream>>>(f32buf, xq32, g3, be3, (float*)d_out,
                                    nullptr);
}